// Round 19
// baseline (219.574 us; speedup 1.0000x reference)
//
#include <hip/hip_runtime.h>
#include <hip/hip_fp16.h>

constexpr int Bz = 8, Nn = 2000, Ee = 32000, NTOT = 16000;
constexpr int XG_OFF = 0, PG_OFF = 160000, EF_OFF = 208000;
#define SLOPE 0.2f
#define EPSL 1e-5f

typedef __attribute__((ext_vector_type(8))) _Float16 f16x8;
typedef __attribute__((ext_vector_type(4))) float float4v;

__device__ __forceinline__ float lrelu(float x) { return x > 0.f ? x : SLOPE * x; }

__device__ __forceinline__ unsigned short f2h(float x) {
  _Float16 hh = (_Float16)x;
  return *(unsigned short*)&hh;
}

__device__ __forceinline__ float wave_max(float v) {
  for (int o = 32; o; o >>= 1) v = fmaxf(v, __shfl_xor(v, o));
  return v;
}
__device__ __forceinline__ float wave_sum(float v) {
  for (int o = 32; o; o >>= 1) v += __shfl_xor(v, o);
  return v;
}

// ---------------- CSR build ----------------
__global__ void hist_k(const int* __restrict__ tei, int* __restrict__ counts) {
  int j = blockIdx.x * 256 + threadIdx.x;
  if (j < Ee) atomicAdd(&counts[tei[Ee + j]], 1);
}

__global__ void scan_k(const int* __restrict__ counts, int* __restrict__ offs) {
  __shared__ int part[256];
  int t = threadIdx.x;
  int loc[8];
  int s = 0;
  for (int i = 0; i < 8; i++) {
    int idx = t * 8 + i;
    int c = (idx < Nn) ? counts[idx] : 0;
    loc[i] = s; s += c;
  }
  part[t] = s;
  __syncthreads();
  for (int o = 1; o < 256; o <<= 1) {
    int v = (t >= o) ? part[t - o] : 0;
    __syncthreads();
    part[t] += v;
    __syncthreads();
  }
  int excl = (t == 0) ? 0 : part[t - 1];
  for (int i = 0; i < 8; i++) {
    int idx = t * 8 + i;
    if (idx < Nn) offs[idx] = excl + loc[i];
  }
  if (t == 255) offs[Nn] = part[255];
}

__global__ void place_k(const int* __restrict__ tei, const int* __restrict__ offs,
                        int* __restrict__ cursor, int* __restrict__ colb) {
  int j = blockIdx.x * 256 + threadIdx.x;
  if (j < Ee) {
    int d = tei[Ee + j];
    int slot = offs[d] + atomicAdd(&cursor[d], 1);
    colb[slot] = tei[j];
  }
}

// ---------------- small dense layers ----------------
template <int K, int ACT>
__global__ __launch_bounds__(256) void lin_k(const float* __restrict__ x, const float* __restrict__ w,
                                             const float* __restrict__ bias, float* __restrict__ y,
                                             int O) {
  int gw = blockIdx.x * 4 + (threadIdx.x >> 6);
  int lane = threadIdx.x & 63;
  int bb = gw / O, o = gw - bb * O;
  float acc = 0.f;
#pragma unroll
  for (int k = lane; k < K; k += 64) acc += x[bb * K + k] * w[k * O + o];
  acc = wave_sum(acc);
  if (lane == 0) {
    if (bias) acc += bias[o];
    y[gw] = ACT ? lrelu(acc) : acc;
  }
}

// Fused weight preps: blk<256 -> w2bf, blk==256 -> w3t, blk>=257 -> tp16(nl=blk-257)
__global__ __launch_bounds__(256) void prep_k(const float* __restrict__ g2w, unsigned short* __restrict__ Bt,
                                              const float* __restrict__ g3w, unsigned short* __restrict__ W3t,
                                              const float* __restrict__ tx, const float* __restrict__ g1w,
                                              const float* __restrict__ a_s, const float* __restrict__ a_d,
                                              unsigned short* __restrict__ tp16, float* __restrict__ tpa,
                                              float* __restrict__ tpd) {
  int blk = blockIdx.x;
  if (blk < 256) {
    __shared__ float tile[32][33];
    int txi = threadIdx.x & 31, ty = threadIdx.x >> 5;
    int x0 = (blk & 15) * 32, y0 = (blk >> 4) * 32;
    for (int r = ty; r < 32; r += 8) tile[r][txi] = g2w[(y0 + r) * 512 + x0 + txi];
    __syncthreads();
    for (int r = ty; r < 32; r += 8) {
      unsigned short v = f2h(tile[txi][r]);
      size_t off = (size_t)(x0 + r) * 512 + (y0 + txi);
#pragma unroll
      for (int cp = 0; cp < 8; cp++) Bt[cp * 262144 + off] = v;
    }
  } else if (blk == 256) {
    for (int idx = threadIdx.x; idx < 8192; idx += 256) {
      int col = idx >> 9, k = idx & 511;
      float v = (col < 13) ? g3w[k * 13 + col] : 0.f;
      W3t[idx] = f2h(v);
    }
  } else {
    int nl = blk - 257;
    int head = threadIdx.x >> 6, lane = threadIdx.x & 63;
    int c = head * 128 + 2 * lane;
    float t0 = 0.f, t1 = 0.f;
#pragma unroll
    for (int k = 0; k < 10; k++) {
      float xv = tx[nl * 10 + k];
      float2 wv = *(const float2*)&g1w[k * 512 + c];
      t0 += xv * wv.x; t1 += xv * wv.y;
    }
    ushort2 st; st.x = f2h(t0); st.y = f2h(t1);
    *(ushort2*)&tp16[(size_t)nl * 512 + c] = st;
    float2 av = *(const float2*)&a_s[c];
    float2 dv = *(const float2*)&a_d[c];
    float pa = wave_sum(t0 * av.x + t1 * av.y);
    float pd = wave_sum(t0 * dv.x + t1 * dv.y);
    if (lane == 0) { tpa[nl * 4 + head] = pa; tpd[nl * 4 + head] = pd; }
  }
}

// Fused s = l2@w3+b3 -> pb = s@g1w[10:] -> pba/pbd. One block per batch.
__global__ __launch_bounds__(256) void spb_k(const float* __restrict__ l2, const float* __restrict__ w3,
                                             const float* __restrict__ b3, const float* __restrict__ g1w,
                                             const float* __restrict__ a_s, const float* __restrict__ a_d,
                                             float* __restrict__ pb, float* __restrict__ pba,
                                             float* __restrict__ pbd) {
  int b = blockIdx.x;
  int t = threadIdx.x;
  __shared__ float l2s[512];
  __shared__ float ss[64];
  __shared__ float pbs[512];
  l2s[t] = l2[b * 512 + t];
  l2s[t + 256] = l2[b * 512 + t + 256];
  __syncthreads();
  if (t < 64) {
    float acc = b3[t];
    for (int k = 0; k < 512; k++) acc += l2s[k] * w3[k * 64 + t];
    ss[t] = acc;
  }
  __syncthreads();
  for (int o = t; o < 512; o += 256) {
    float acc = 0.f;
#pragma unroll
    for (int k = 0; k < 64; k++) acc += ss[k] * g1w[(10 + k) * 512 + o];
    pbs[o] = acc;
    pb[b * 512 + o] = acc;
  }
  __syncthreads();
  int w = t >> 6, lane = t & 63;
  int c = w * 128 + 2 * lane;
  float2 pv = *(float2*)&pbs[c];
  float2 av = *(const float2*)&a_s[c];
  float2 dv = *(const float2*)&a_d[c];
  float pa = wave_sum(pv.x * av.x + pv.y * av.y);
  float pd = wave_sum(pv.x * dv.x + pv.y * dv.y);
  if (lane == 0) { pba[b * 4 + w] = pa; pbd[b * 4 + w] = pd; }
}

// GAT1 aggregation from template table + LN (round-17 form: node-per-batch blocks)
__global__ __launch_bounds__(256) void agg1_k(const unsigned short* __restrict__ tp16,
                                              const float* __restrict__ tpa, const float* __restrict__ tpd,
                                              const float* __restrict__ pba, const float* __restrict__ pbd,
                                              const float* __restrict__ pb,
                                              const float* __restrict__ bias,
                                              const float* __restrict__ g, const float* __restrict__ beta,
                                              unsigned short* __restrict__ out,
                                              const int* __restrict__ offs, const int* __restrict__ colb) {
  int blk = blockIdx.x;
  int b = blk & 7, nl = blk >> 3;
  int n = b * Nn + nl;
  int w = threadIdx.x >> 6, lane = threadIdx.x & 63;
  int rs = offs[nl];
  int nit = offs[nl + 1] - rs + 1;
  float aldn = tpd[nl * 4 + w] + pbd[b * 4 + w];
  float pbsrc = pba[b * 4 + w];

  __shared__ unsigned int alpha_u[4][68];
  __shared__ int sgn[64];
  __shared__ float part[4][512];
  __shared__ float invs[4];
  __shared__ float red[8];
  __shared__ float bcs[2];

  __half2 acc2[4];
#pragma unroll
  for (int j = 0; j < 4; j++) acc2[j] = __float2half2_rn(0.f);

  const unsigned short* hbase = tp16 + lane * 8;
  int hd = lane >> 4;

  if (nit <= 64) {
    int se = nl;
    float logit = -3e38f;
    if (lane < nit) {
      se = (lane < nit - 1) ? colb[rs + lane] : nl;
      logit = lrelu(tpa[se * 4 + w] + pbsrc + aldn);
    }
    if (w == 0) sgn[lane] = se;
    float m = wave_max(logit);
    float raw = (lane < nit) ? __expf(logit - m) : 0.f;
    float den = wave_sum(raw);
    if (lane == 0) invs[w] = 1.f / den;
    __half2 a2 = __float2half2_rn(raw);
    alpha_u[w][lane] = *(unsigned int*)&a2;
    __syncthreads();
    int e = w;
    for (; e + 12 < nit; e += 16) {
      uint4 hv[4];
      unsigned int au[4];
#pragma unroll
      for (int i = 0; i < 4; i++) {
        int ei = e + i * 4;
        au[i] = alpha_u[hd][ei];
        hv[i] = *(const uint4*)(hbase + (size_t)sgn[ei] * 512);
      }
#pragma unroll
      for (int i = 0; i < 4; i++) {
        __half2 a2e = *(__half2*)&au[i];
        acc2[0] = __hfma2(a2e, *(__half2*)&hv[i].x, acc2[0]);
        acc2[1] = __hfma2(a2e, *(__half2*)&hv[i].y, acc2[1]);
        acc2[2] = __hfma2(a2e, *(__half2*)&hv[i].z, acc2[2]);
        acc2[3] = __hfma2(a2e, *(__half2*)&hv[i].w, acc2[3]);
      }
    }
    for (; e < nit; e += 4) {
      unsigned int au = alpha_u[hd][e];
      uint4 hv = *(const uint4*)(hbase + (size_t)sgn[e] * 512);
      __half2 a2e = *(__half2*)&au;
      acc2[0] = __hfma2(a2e, *(__half2*)&hv.x, acc2[0]);
      acc2[1] = __hfma2(a2e, *(__half2*)&hv.y, acc2[1]);
      acc2[2] = __hfma2(a2e, *(__half2*)&hv.z, acc2[2]);
      acc2[3] = __hfma2(a2e, *(__half2*)&hv.w, acc2[3]);
    }
  } else {
    float m = -3e38f;
    for (int i = lane; i < nit; i += 64) {
      int se = (i < nit - 1) ? colb[rs + i] : nl;
      m = fmaxf(m, lrelu(tpa[se * 4 + w] + pbsrc + aldn));
    }
    m = wave_max(m);
    float den = 0.f;
    for (int base = 0; base < nit; base += 64) {
      int cnt = min(64, nit - base);
      int se = nl;
      float raw = 0.f;
      if (lane < cnt) {
        int i = base + lane;
        se = (i < nit - 1) ? colb[rs + i] : nl;
        raw = __expf(lrelu(tpa[se * 4 + w] + pbsrc + aldn) - m);
      }
      if (w == 0) sgn[lane] = se;
      den += raw;
      __half2 a2 = __float2half2_rn(raw);
      alpha_u[w][lane] = *(unsigned int*)&a2;
      __syncthreads();
      for (int e = w; e < cnt; e += 4) {
        unsigned int au = alpha_u[hd][e];
        uint4 hv = *(const uint4*)(hbase + (size_t)sgn[e] * 512);
        __half2 a2e = *(__half2*)&au;
        acc2[0] = __hfma2(a2e, *(__half2*)&hv.x, acc2[0]);
        acc2[1] = __hfma2(a2e, *(__half2*)&hv.y, acc2[1]);
        acc2[2] = __hfma2(a2e, *(__half2*)&hv.z, acc2[2]);
        acc2[3] = __hfma2(a2e, *(__half2*)&hv.w, acc2[3]);
      }
      __syncthreads();
    }
    den = wave_sum(den);
    if (lane == 0) invs[w] = 1.f / den;
  }

  float fv[8];
#pragma unroll
  for (int j = 0; j < 4; j++) {
    float2 f2 = __half22float2(acc2[j]);
    fv[2 * j] = f2.x; fv[2 * j + 1] = f2.y;
  }
  *(float4*)&part[w][lane * 8] = make_float4(fv[0], fv[1], fv[2], fv[3]);
  *(float4*)&part[w][lane * 8 + 4] = make_float4(fv[4], fv[5], fv[6], fv[7]);
  __syncthreads();

  int c = 2 * (int)threadIdx.x;
  float inv = invs[c >> 7];
  float s0 = part[0][c] + part[1][c] + part[2][c] + part[3][c];
  float s1 = part[0][c + 1] + part[1][c + 1] + part[2][c + 1] + part[3][c + 1];
  float2 pv = *(const float2*)&pb[b * 512 + c];
  float v0 = lrelu(s0 * inv + pv.x + bias[c]);
  float v1 = lrelu(s1 * inv + pv.y + bias[c + 1]);
  float p1 = wave_sum(v0 + v1);
  float p2 = wave_sum(v0 * v0 + v1 * v1);
  if (lane == 0) { red[w] = p1; red[4 + w] = p2; }
  __syncthreads();
  if (threadIdx.x == 0) {
    float s1r = red[0] + red[1] + red[2] + red[3];
    float s2r = red[4] + red[5] + red[6] + red[7];
    float mu = s1r * (1.f / 512.f);
    float var = s2r * (1.f / 512.f) - mu * mu;
    bcs[0] = mu;
    bcs[1] = rsqrtf(var + EPSL);
  }
  __syncthreads();
  float mu = bcs[0], rstd = bcs[1];
  float o0 = (v0 - mu) * rstd * g[c] + beta[c];
  float o1 = (v1 - mu) * rstd * g[c + 1] + beta[c + 1];
  ushort2 st; st.x = f2h(o0); st.y = f2h(o1);
  *(ushort2*)&out[(size_t)n * 512 + c] = st;
}

// GAT2 aggregation + bias + leaky + resid + LayerNorm
__global__ __launch_bounds__(256) void agg_k(const unsigned short* __restrict__ h,
                                             const float* __restrict__ als, const float* __restrict__ ald,
                                             const float* __restrict__ bias,
                                             const float* __restrict__ g, const float* __restrict__ beta,
                                             const unsigned short* __restrict__ resid,
                                             unsigned short* __restrict__ out,
                                             const int* __restrict__ offs, const int* __restrict__ colb) {
  int blk = blockIdx.x;
  int b = blk & 7, nl = blk >> 3;
  int n = b * Nn + nl;
  int w = threadIdx.x >> 6, lane = threadIdx.x & 63;
  int rs = offs[nl];
  int nit = offs[nl + 1] - rs + 1;
  float aldn = ald[n * 4 + w];

  __shared__ unsigned int alpha_u[4][68];
  __shared__ int sgn[64];
  __shared__ float part[4][512];
  __shared__ float invs[4];
  __shared__ float red[8];
  __shared__ float bcs[2];

  __half2 acc2[4];
#pragma unroll
  for (int j = 0; j < 4; j++) acc2[j] = __float2half2_rn(0.f);

  const unsigned short* hbase = h + lane * 8;
  int hd = lane >> 4;

  if (nit <= 64) {
    int sg = n;
    float logit = -3e38f;
    if (lane < nit) {
      sg = (lane < nit - 1) ? colb[rs + lane] + b * Nn : n;
      logit = lrelu(als[sg * 4 + w] + aldn);
    }
    if (w == 0) sgn[lane] = sg;
    float m = wave_max(logit);
    float raw = (lane < nit) ? __expf(logit - m) : 0.f;
    float den = wave_sum(raw);
    if (lane == 0) invs[w] = 1.f / den;
    __half2 a2 = __float2half2_rn(raw);
    alpha_u[w][lane] = *(unsigned int*)&a2;
    __syncthreads();
    int e = w;
    for (; e + 12 < nit; e += 16) {
      uint4 hv[4];
      unsigned int au[4];
#pragma unroll
      for (int i = 0; i < 4; i++) {
        int ei = e + i * 4;
        au[i] = alpha_u[hd][ei];
        hv[i] = *(const uint4*)(hbase + (size_t)sgn[ei] * 512);
      }
#pragma unroll
      for (int i = 0; i < 4; i++) {
        __half2 a2e = *(__half2*)&au[i];
        acc2[0] = __hfma2(a2e, *(__half2*)&hv[i].x, acc2[0]);
        acc2[1] = __hfma2(a2e, *(__half2*)&hv[i].y, acc2[1]);
        acc2[2] = __hfma2(a2e, *(__half2*)&hv[i].z, acc2[2]);
        acc2[3] = __hfma2(a2e, *(__half2*)&hv[i].w, acc2[3]);
      }
    }
    for (; e < nit; e += 4) {
      unsigned int au = alpha_u[hd][e];
      uint4 hv = *(const uint4*)(hbase + (size_t)sgn[e] * 512);
      __half2 a2e = *(__half2*)&au;
      acc2[0] = __hfma2(a2e, *(__half2*)&hv.x, acc2[0]);
      acc2[1] = __hfma2(a2e, *(__half2*)&hv.y, acc2[1]);
      acc2[2] = __hfma2(a2e, *(__half2*)&hv.z, acc2[2]);
      acc2[3] = __hfma2(a2e, *(__half2*)&hv.w, acc2[3]);
    }
  } else {
    float m = -3e38f;
    for (int i = lane; i < nit; i += 64) {
      int sg = (i < nit - 1) ? colb[rs + i] + b * Nn : n;
      m = fmaxf(m, lrelu(als[sg * 4 + w] + aldn));
    }
    m = wave_max(m);
    float den = 0.f;
    for (int base = 0; base < nit; base += 64) {
      int cnt = min(64, nit - base);
      int sg = n;
      float raw = 0.f;
      if (lane < cnt) {
        int i = base + lane;
        sg = (i < nit - 1) ? colb[rs + i] + b * Nn : n;
        raw = __expf(lrelu(als[sg * 4 + w] + aldn) - m);
      }
      if (w == 0) sgn[lane] = sg;
      den += raw;
      __half2 a2 = __float2half2_rn(raw);
      alpha_u[w][lane] = *(unsigned int*)&a2;
      __syncthreads();
      for (int e = w; e < cnt; e += 4) {
        unsigned int au = alpha_u[hd][e];
        uint4 hv = *(const uint4*)(hbase + (size_t)sgn[e] * 512);
        __half2 a2e = *(__half2*)&au;
        acc2[0] = __hfma2(a2e, *(__half2*)&hv.x, acc2[0]);
        acc2[1] = __hfma2(a2e, *(__half2*)&hv.y, acc2[1]);
        acc2[2] = __hfma2(a2e, *(__half2*)&hv.z, acc2[2]);
        acc2[3] = __hfma2(a2e, *(__half2*)&hv.w, acc2[3]);
      }
      __syncthreads();
    }
    den = wave_sum(den);
    if (lane == 0) invs[w] = 1.f / den;
  }

  float fv[8];
#pragma unroll
  for (int j = 0; j < 4; j++) {
    float2 f2 = __half22float2(acc2[j]);
    fv[2 * j] = f2.x; fv[2 * j + 1] = f2.y;
  }
  *(float4*)&part[w][lane * 8] = make_float4(fv[0], fv[1], fv[2], fv[3]);
  *(float4*)&part[w][lane * 8 + 4] = make_float4(fv[4], fv[5], fv[6], fv[7]);
  __syncthreads();

  int c = 2 * (int)threadIdx.x;
  float inv = invs[c >> 7];
  float s0 = part[0][c] + part[1][c] + part[2][c] + part[3][c];
  float s1 = part[0][c + 1] + part[1][c + 1] + part[2][c + 1] + part[3][c + 1];
  float v0 = lrelu(s0 * inv + bias[c]);
  float v1 = lrelu(s1 * inv + bias[c + 1]);
  unsigned int rv = *(const unsigned int*)&resid[(size_t)n * 512 + c];
  __half2 rh = *(__half2*)&rv;
  float2 rf = __half22float2(rh);
  v0 += rf.x; v1 += rf.y;
  float p1 = wave_sum(v0 + v1);
  float p2 = wave_sum(v0 * v0 + v1 * v1);
  if (lane == 0) { red[w] = p1; red[4 + w] = p2; }
  __syncthreads();
  if (threadIdx.x == 0) {
    float s1r = red[0] + red[1] + red[2] + red[3];
    float s2r = red[4] + red[5] + red[6] + red[7];
    float mu = s1r * (1.f / 512.f);
    float var = s2r * (1.f / 512.f) - mu * mu;
    bcs[0] = mu;
    bcs[1] = rsqrtf(var + EPSL);
  }
  __syncthreads();
  float mu = bcs[0], rstd = bcs[1];
  float o0 = (v0 - mu) * rstd * g[c] + beta[c];
  float o1 = (v1 - mu) * rstd * g[c + 1] + beta[c + 1];
  ushort2 st; st.x = f2h(o0); st.y = f2h(o1);
  *(ushort2*)&out[(size_t)n * 512 + c] = st;
}

// ---------------- MFMA GEMM, B-RESIDENT, barrier-free K-loop + atomic als2/ald2 partials ----------------
__global__ __launch_bounds__(256) void gemm2_k(const unsigned short* __restrict__ A,
                                               const unsigned short* __restrict__ Bt,
                                               unsigned short* __restrict__ C,
                                               const float* __restrict__ As, const float* __restrict__ Ad,
                                               float* __restrict__ als2, float* __restrict__ ald2) {
  __shared__ unsigned short sB[64][520];
  int t = threadIdx.x;
  int lane = t & 63, w = t >> 6;
  int m0 = blockIdx.x * 128;
  int n0 = blockIdx.y * 64;
  const unsigned short* Bl = Bt + (size_t)((blockIdx.x + blockIdx.y * 125) & 7) * 262144;

#pragma unroll
  for (int q = 0; q < 16; q++) {
    int slot = q * 256 + t;
    int row = slot >> 6, c16 = (slot & 63) * 8;
    *(uint4*)&sB[row][c16] = *(const uint4*)(Bl + (size_t)(n0 + row) * 512 + c16);
  }
  __syncthreads();

  float4v acc[2][4];
#pragma unroll
  for (int m = 0; m < 2; m++)
#pragma unroll
    for (int nn = 0; nn < 4; nn++) acc[m][nn] = (float4v){0.f, 0.f, 0.f, 0.f};

  int r0 = m0 + w * 32 + (lane & 15);
  int kb = (lane >> 4) * 8;
  const unsigned short* a0p = A + (size_t)r0 * 512 + kb;
  const unsigned short* a1p = A + (size_t)(r0 + 16) * 512 + kb;
  int bc = lane & 15;

#pragma unroll
  for (int kf = 0; kf < 16; kf++) {
    int k0 = kf * 32;
    f16x8 af0 = *(const f16x8*)(a0p + k0);
    f16x8 af1 = *(const f16x8*)(a1p + k0);
    f16x8 bg0 = *(const f16x8*)&sB[bc][k0 + kb];
    f16x8 bg1 = *(const f16x8*)&sB[16 + bc][k0 + kb];
    f16x8 bg2 = *(const f16x8*)&sB[32 + bc][k0 + kb];
    f16x8 bg3 = *(const f16x8*)&sB[48 + bc][k0 + kb];
    acc[0][0] = __builtin_amdgcn_mfma_f32_16x16x32_f16(af0, bg0, acc[0][0], 0, 0, 0);
    acc[0][1] = __builtin_amdgcn_mfma_f32_16x16x32_f16(af0, bg1, acc[0][1], 0, 0, 0);
    acc[0][2] = __builtin_amdgcn_mfma_f32_16x16x32_f16(af0, bg2, acc[0][2], 0, 0, 0);
    acc[0][3] = __builtin_amdgcn_mfma_f32_16x16x32_f16(af0, bg3, acc[0][3], 0, 0, 0);
    acc[1][0] = __builtin_amdgcn_mfma_f32_16x16x32_f16(af1, bg0, acc[1][0], 0, 0, 0);
    acc[1][1] = __builtin_amdgcn_mfma_f32_16x16x32_f16(af1, bg1, acc[1][1], 0, 0, 0);
    acc[1][2] = __builtin_amdgcn_mfma_f32_16x16x32_f16(af1, bg2, acc[1][2], 0, 0, 0);
    acc[1][3] = __builtin_amdgcn_mfma_f32_16x16x32_f16(af1, bg3, acc[1][3], 0, 0, 0);
  }

  // als2/ald2 partials
  {
    int head = n0 >> 7;
    int cb = n0 & 127;
    float asv[4], adv[4];
#pragma unroll
    for (int nn = 0; nn < 4; nn++) {
      asv[nn] = As[head * 128 + cb + nn * 16 + bc];
      adv[nn] = Ad[head * 128 + cb + nn * 16 + bc];
    }
#pragma unroll
    for (int m = 0; m < 2; m++) {
#pragma unroll
      for (int r = 0; r < 4; r++) {
        float pa = 0.f, pd = 0.f;
#pragma unroll
        for (int nn = 0; nn < 4; nn++) { pa += acc[m][nn][r] * asv[nn]; pd += acc[m][nn][r] * adv[nn]; }
        for (int o = 1; o < 16; o <<= 1) { pa += __shfl_xor(pa, o); pd += __shfl_xor(pd, o); }
        if ((lane & 15) == 0) {
          int row = m0 + w * 32 + (lane >> 4) * 4 + m * 16 + r;
          atomicAdd(&als2[row * 4 + head], pa);
          atomicAdd(&ald2[row * 4 + head], pd);
        }
      }
    }
  }

  // C store via LDS restage; stride 72 ushorts (144B)
  __syncthreads();
  unsigned short* sC = &sB[0][0];
  int rb = w * 32 + (lane >> 4) * 4;
#pragma unroll
  for (int m = 0; m < 2; m++)
#pragma unroll
    for (int nn = 0; nn < 4; nn++)
#pragma unroll
      for (int r = 0; r < 4; r++)
        sC[(rb + m * 16 + r) * 72 + bc + nn * 16] = f2h(acc[m][nn][r]);
  __syncthreads();
#pragma unroll
  for (int p = 0; p < 4; p++) {
    int row = p * 32 + (t >> 3);
    int co = (t & 7) * 8;
    uint4 v = *(const uint4*)&sC[row * 72 + co];
    *(uint4*)&C[(size_t)(m0 + row) * 512 + n0 + co] = v;
  }
}

// ---------------- GAT3 GEMM ----------------
__global__ __launch_bounds__(256) void gemm3_k(const unsigned short* __restrict__ H,
                                               const unsigned short* __restrict__ W3t,
                                               const float* __restrict__ as3, const float* __restrict__ ad3,
                                               float* __restrict__ h3, float* __restrict__ als3,
                                               float* __restrict__ ald3) {
  int w = threadIdx.x >> 6, l = threadIdx.x & 63;
  int blk = blockIdx.x;
  int b = blk & 7, i = blk >> 3;
  int base = i * 64 + w * 16;
  int r16 = l & 15, g4 = l >> 4;
  int lrow_ld = min(base + r16, Nn - 1);
  float4v acc = (float4v){0.f, 0.f, 0.f, 0.f};
  const unsigned short* ha = H + (size_t)(b * Nn + lrow_ld) * 512 + g4 * 8;
  const unsigned short* wb = W3t + (size_t)r16 * 512 + g4 * 8;
#pragma unroll
  for (int kk = 0; kk < 16; kk++) {
    f16x8 a = *(const f16x8*)(ha + kk * 32);
    f16x8 bfr = *(const f16x8*)(wb + kk * 32);
    acc = __builtin_amdgcn_mfma_f32_16x16x32_f16(a, bfr, acc, 0, 0, 0);
  }
  int col = r16;
  float asv = (col < 13) ? as3[col] : 0.f;
  float adv = (col < 13) ? ad3[col] : 0.f;
#pragma unroll
  for (int r = 0; r < 4; r++) {
    float v = acc[r];
    int lrow = base + g4 * 4 + r;
    if (lrow < Nn) {
      int row = b * Nn + lrow;
      if (col < 13) h3[row * 13 + col] = v;
      float sa = v * asv, sd = v * adv;
      for (int o = 1; o < 16; o <<= 1) { sa += __shfl_xor(sa, o); sd += __shfl_xor(sd, o); }
      if (col == 0) { als3[row] = sa; ald3[row] = sd; }
    }
  }
}

// GAT3 aggregation + output assembly
__global__ __launch_bounds__(64) void agg3_k(const float* __restrict__ h3, const float* __restrict__ als3,
                                             const float* __restrict__ ald3, const float* __restrict__ b3,
                                             const float* __restrict__ tx, const int* __restrict__ offs,
                                             const int* __restrict__ colb, float* __restrict__ dout) {
  int blk = blockIdx.x, lane = threadIdx.x;
  int b = blk & 7, nl = blk >> 3;
  int n = b * Nn + nl;
  int rs = offs[nl], deg = offs[nl + 1] - rs;
  float aldn = ald3[n];
  float sl = lrelu(als3[n] + aldn);
  float a = 0.f, inv;
  if (deg <= 64) {
    int sgl = 0; float logit = -1e30f;
    if (lane < deg) { sgl = colb[rs + lane] + b * Nn; logit = lrelu(als3[sgl] + aldn); }
    float m = wave_max(fmaxf(logit, sl));
    float raw = (lane < deg) ? __expf(logit - m) : 0.f;
    float es = __expf(sl - m);
    inv = 1.f / (wave_sum(raw) + es);
    if (lane < 13) a = es * h3[n * 13 + lane];
    for (int e = 0; e < deg; e++) {
      float w = __shfl(raw, e);
      int sg = __shfl(sgl, e);
      if (lane < 13) a += w * h3[sg * 13 + lane];
    }
  } else {
    float m = sl;
    for (int e = lane; e < deg; e += 64) {
      int sg = colb[rs + e] + b * Nn;
      m = fmaxf(m, lrelu(als3[sg] + aldn));
    }
    m = wave_max(m);
    float es = __expf(sl - m);
    float den = (lane == 0) ? es : 0.f;
    if (lane < 13) a = es * h3[n * 13 + lane];
    for (int base = 0; base < deg; base += 64) {
      int cnt = min(64, deg - base);
      int sgl = 0; float raw = 0.f;
      if (lane < cnt) {
        sgl = colb[rs + base + lane] + b * Nn;
        raw = __expf(lrelu(als3[sgl] + aldn) - m);
      }
      den += raw;
      for (int e = 0; e < cnt; e++) {
        float w = __shfl(raw, e);
        int sg = __shfl(sgl, e);
        if (lane < 13) a += w * h3[sg * 13 + lane];
      }
    }
    inv = 1.f / wave_sum(den);
  }
  a *= inv;
  float hv = a + ((lane < 13) ? b3[lane] : 0.f);
  float txv = (lane < 10) ? tx[nl * 10 + lane] : 0.f;
  float pv = txv + hv;
  if (lane < 3) dout[PG_OFF + n * 3 + lane] = pv;
  float up = __shfl(hv, lane + 3);
  float xg = (lane < 3) ? pv : (txv + up);
  if (lane < 10) dout[XG_OFF + n * 10 + lane] = xg;
}

__global__ void ef_k(const int* __restrict__ tei, float* __restrict__ dout) {
  int blk = blockIdx.x;
  int b = blk & 7, i = blk >> 3;
  int j = i * 256 + threadIdx.x;
  int e = b * Ee + j;
  int sg = tei[j] + b * Nn;
  int dg = tei[Ee + j] + b * Nn;
  const float* pg = dout + PG_OFF;
  dout[EF_OFF + e * 3 + 0] = pg[dg * 3 + 0] - pg[sg * 3 + 0];
  dout[EF_OFF + e * 3 + 1] = pg[dg * 3 + 1] - pg[sg * 3 + 1];
  dout[EF_OFF + e * 3 + 2] = pg[dg * 3 + 2] - pg[sg * 3 + 2];
}

extern "C" void kernel_launch(void* const* d_in, const int* in_sizes, int n_in,
                              void* d_out, int out_size, void* d_ws, size_t ws_size,
                              hipStream_t stream) {
  const float* z = (const float*)d_in[0];
  const float* tx = (const float*)d_in[1];
  const int* tei = (const int*)d_in[2];
  const float* w1 = (const float*)d_in[3];
  const float* b1 = (const float*)d_in[4];
  const float* w2 = (const float*)d_in[5];
  const float* b2 = (const float*)d_in[6];
  const float* w3 = (const float*)d_in[7];
  const float* b3 = (const float*)d_in[8];
  const float* g1w = (const float*)d_in[9];
  const float* g1as = (const float*)d_in[10];
  const float* g1ad = (const float*)d_in[11];
  const float* g1b = (const float*)d_in[12];
  const float* ln1g = (const float*)d_in[13];
  const float* ln1b = (const float*)d_in[14];
  const float* g2w = (const float*)d_in[15];
  const float* g2as = (const float*)d_in[16];
  const float* g2ad = (const float*)d_in[17];
  const float* g2b = (const float*)d_in[18];
  const float* ln2g = (const float*)d_in[19];
  const float* ln2b = (const float*)d_in[20];
  const float* g3w = (const float*)d_in[21];
  const float* g3as = (const float*)d_in[22];
  const float* g3ad = (const float*)d_in[23];
  const float* g3b = (const float*)d_in[24];
  float* out = (float*)d_out;

  float* F = (float*)d_ws;
  float* pb_ = F + 0;
  float* l1_ = F + 8192;
  float* l2_ = F + 16384;
  float* pba_ = F + 30000;
  float* pbd_ = F + 30100;
  float* tpa_ = F + 100000;
  float* tpd_ = F + 164000;
  float* als2 = F + 228000;   // 64000, contiguous with ald2
  float* ald2 = F + 292000;   // 64000
  float* als3 = F + 356000;
  float* ald3 = F + 372000;
  float* h3_ = F + 388000;
  unsigned short* U = (unsigned short*)(F + 600000);
  unsigned short* hA = U;
  unsigned short* hB = U + 8192000;
  unsigned short* Bt = U + 16384000;
  unsigned short* W3t = U + 18481152;
  unsigned short* tp16 = U + 18489344;
  int* I = (int*)(F + 12000000);
  int* counts = I;
  int* cursor = I + 2000;
  int* offs = I + 4000;
  int* colb = I + 6001;

  // zero CSR scratch + als2/ald2 accumulators (contiguous -> one memset)
  hipMemsetAsync(counts, 0, 4000 * sizeof(int), stream);
  hipMemsetAsync(als2, 0, 128000 * sizeof(float), stream);

  // CSR of template graph
  hist_k<<<125, 256, 0, stream>>>(tei, counts);
  scan_k<<<1, 256, 0, stream>>>(counts, offs);
  place_k<<<125, 256, 0, stream>>>(tei, offs, cursor, colb);

  // fused weight preps + template table (w2bf | w3t | tp16)
  prep_k<<<2257, 256, 0, stream>>>(g2w, Bt, g3w, W3t, tx, g1w, g1as, g1ad, tp16, tpa_, tpd_);

  // style MLP: l1, l2, then fused {s, pb, pba/pbd}
  lin_k<128, 1><<<512, 256, 0, stream>>>(z, w1, b1, l1_, 256);
  lin_k<256, 1><<<1024, 256, 0, stream>>>(l1_, w2, b2, l2_, 512);
  spb_k<<<8, 256, 0, stream>>>(l2_, w3, b3, g1w, g1as, g1ad, pb_, pba_, pbd_);

  // GAT1 (template gather)
  agg1_k<<<NTOT, 256, 0, stream>>>(tp16, tpa_, tpd_, pba_, pbd_, pb_, g1b, ln1g, ln1b,
                                   hB, offs, colb);

  // GAT2: barrier-free B-resident GEMM w/ atomic als2/ald2, then aggregation
  gemm2_k<<<dim3(125, 8), 256, 0, stream>>>(hB, Bt, hA, g2as, g2ad, als2, ald2);
  agg_k<<<NTOT, 256, 0, stream>>>(hA, als2, ald2, g2b, ln2g, ln2b, hB, hB, offs, colb);

  // GAT3 + outputs
  gemm3_k<<<256, 256, 0, stream>>>(hB, W3t, g3as, g3ad, h3_, als3, ald3);
  agg3_k<<<NTOT, 64, 0, stream>>>(h3_, als3, ald3, g3b, tx, offs, colb, out);
  ef_k<<<1000, 256, 0, stream>>>(tei, out);
}

// Round 20
// 191.572 us; speedup vs baseline: 1.1462x; 1.1462x over previous
//
#include <hip/hip_runtime.h>
#include <hip/hip_fp16.h>

constexpr int Bz = 8, Nn = 2000, Ee = 32000, NTOT = 16000;
constexpr int XG_OFF = 0, PG_OFF = 160000, EF_OFF = 208000;
#define SLOPE 0.2f
#define EPSL 1e-5f

typedef __attribute__((ext_vector_type(8))) _Float16 f16x8;
typedef __attribute__((ext_vector_type(4))) float float4v;

__device__ __forceinline__ float lrelu(float x) { return x > 0.f ? x : SLOPE * x; }

__device__ __forceinline__ unsigned short f2h(float x) {
  _Float16 hh = (_Float16)x;
  return *(unsigned short*)&hh;
}

__device__ __forceinline__ float wave_max(float v) {
  for (int o = 32; o; o >>= 1) v = fmaxf(v, __shfl_xor(v, o));
  return v;
}
__device__ __forceinline__ float wave_sum(float v) {
  for (int o = 32; o; o >>= 1) v += __shfl_xor(v, o);
  return v;
}

// ---------------- CSR build ----------------
__global__ void hist_k(const int* __restrict__ tei, int* __restrict__ counts) {
  int j = blockIdx.x * 256 + threadIdx.x;
  if (j < Ee) atomicAdd(&counts[tei[Ee + j]], 1);
}

__global__ void scan_k(const int* __restrict__ counts, int* __restrict__ offs) {
  __shared__ int part[256];
  int t = threadIdx.x;
  int loc[8];
  int s = 0;
  for (int i = 0; i < 8; i++) {
    int idx = t * 8 + i;
    int c = (idx < Nn) ? counts[idx] : 0;
    loc[i] = s; s += c;
  }
  part[t] = s;
  __syncthreads();
  for (int o = 1; o < 256; o <<= 1) {
    int v = (t >= o) ? part[t - o] : 0;
    __syncthreads();
    part[t] += v;
    __syncthreads();
  }
  int excl = (t == 0) ? 0 : part[t - 1];
  for (int i = 0; i < 8; i++) {
    int idx = t * 8 + i;
    if (idx < Nn) offs[idx] = excl + loc[i];
  }
  if (t == 255) offs[Nn] = part[255];
}

__global__ void place_k(const int* __restrict__ tei, const int* __restrict__ offs,
                        int* __restrict__ cursor, int* __restrict__ colb) {
  int j = blockIdx.x * 256 + threadIdx.x;
  if (j < Ee) {
    int d = tei[Ee + j];
    int slot = offs[d] + atomicAdd(&cursor[d], 1);
    colb[slot] = tei[j];
  }
}

// ---------------- small dense layers ----------------
template <int K, int ACT>
__global__ __launch_bounds__(256) void lin_k(const float* __restrict__ x, const float* __restrict__ w,
                                             const float* __restrict__ bias, float* __restrict__ y,
                                             int O) {
  int gw = blockIdx.x * 4 + (threadIdx.x >> 6);
  int lane = threadIdx.x & 63;
  int bb = gw / O, o = gw - bb * O;
  float acc = 0.f;
#pragma unroll
  for (int k = lane; k < K; k += 64) acc += x[bb * K + k] * w[k * O + o];
  acc = wave_sum(acc);
  if (lane == 0) {
    if (bias) acc += bias[o];
    y[gw] = ACT ? lrelu(acc) : acc;
  }
}

// g2w -> Bt f16, replicated x8
__global__ __launch_bounds__(256) void w2bf_k(const float* __restrict__ W, unsigned short* __restrict__ Bt) {
  __shared__ float tile[32][33];
  int tx = threadIdx.x & 31, ty = threadIdx.x >> 5;
  int x0 = blockIdx.x * 32;
  int y0 = blockIdx.y * 32;
  for (int r = ty; r < 32; r += 8) tile[r][tx] = W[(y0 + r) * 512 + x0 + tx];
  __syncthreads();
  for (int r = ty; r < 32; r += 8) {
    unsigned short v = f2h(tile[tx][r]);
    size_t off = (size_t)(x0 + r) * 512 + (y0 + tx);
#pragma unroll
    for (int cp = 0; cp < 8; cp++) Bt[cp * 262144 + off] = v;
  }
}

// g3w -> W3t [16][512] f16
__global__ void w3t_k(const float* __restrict__ W, unsigned short* __restrict__ W3t) {
  for (int idx = threadIdx.x; idx < 8192; idx += 256) {
    int col = idx >> 9, k = idx & 511;
    float v = (col < 13) ? W[k * 13 + col] : 0.f;
    W3t[idx] = f2h(v);
  }
}

// Template part table + logit dots
__global__ __launch_bounds__(256) void tp16_k(const float* __restrict__ tx, const float* __restrict__ g1w,
                                              const float* __restrict__ a_s, const float* __restrict__ a_d,
                                              unsigned short* __restrict__ tp16, float* __restrict__ tpa,
                                              float* __restrict__ tpd) {
  int nl = blockIdx.x;
  int head = threadIdx.x >> 6, lane = threadIdx.x & 63;
  int c = head * 128 + 2 * lane;
  float t0 = 0.f, t1 = 0.f;
#pragma unroll
  for (int k = 0; k < 10; k++) {
    float xv = tx[nl * 10 + k];
    float2 wv = *(const float2*)&g1w[k * 512 + c];
    t0 += xv * wv.x; t1 += xv * wv.y;
  }
  ushort2 st; st.x = f2h(t0); st.y = f2h(t1);
  *(ushort2*)&tp16[(size_t)nl * 512 + c] = st;
  float2 av = *(const float2*)&a_s[c];
  float2 dv = *(const float2*)&a_d[c];
  float pa = wave_sum(t0 * av.x + t1 * av.y);
  float pd = wave_sum(t0 * dv.x + t1 * dv.y);
  if (lane == 0) { tpa[nl * 4 + head] = pa; tpd[nl * 4 + head] = pd; }
}

// Per-batch logit dots
__global__ void pba_k(const float* __restrict__ pb, const float* __restrict__ a_s,
                      const float* __restrict__ a_d, float* __restrict__ pba, float* __restrict__ pbd) {
  int b = blockIdx.x >> 2, h = blockIdx.x & 3;
  int lane = threadIdx.x;
  int c = h * 128 + 2 * lane;
  float2 pv = *(const float2*)&pb[b * 512 + c];
  float2 av = *(const float2*)&a_s[c];
  float2 dv = *(const float2*)&a_d[c];
  float pa = wave_sum(pv.x * av.x + pv.y * av.y);
  float pd = wave_sum(pv.x * dv.x + pv.y * dv.y);
  if (lane == 0) { pba[b * 4 + h] = pa; pbd[b * 4 + h] = pd; }
}

// GAT1 aggregation from template table + LN
__global__ __launch_bounds__(256) void agg1_k(const unsigned short* __restrict__ tp16,
                                              const float* __restrict__ tpa, const float* __restrict__ tpd,
                                              const float* __restrict__ pba, const float* __restrict__ pbd,
                                              const float* __restrict__ pb,
                                              const float* __restrict__ bias,
                                              const float* __restrict__ g, const float* __restrict__ beta,
                                              unsigned short* __restrict__ out,
                                              const int* __restrict__ offs, const int* __restrict__ colb) {
  int blk = blockIdx.x;
  int b = blk & 7, nl = blk >> 3;
  int n = b * Nn + nl;
  int w = threadIdx.x >> 6, lane = threadIdx.x & 63;
  int rs = offs[nl];
  int nit = offs[nl + 1] - rs + 1;
  float aldn = tpd[nl * 4 + w] + pbd[b * 4 + w];
  float pbsrc = pba[b * 4 + w];

  __shared__ unsigned int alpha_u[4][68];
  __shared__ int sgn[64];
  __shared__ float part[4][512];
  __shared__ float invs[4];
  __shared__ float red[8];
  __shared__ float bcs[2];

  __half2 acc2[4];
#pragma unroll
  for (int j = 0; j < 4; j++) acc2[j] = __float2half2_rn(0.f);

  const unsigned short* hbase = tp16 + lane * 8;
  int hd = lane >> 4;

  if (nit <= 64) {
    int se = nl;
    float logit = -3e38f;
    if (lane < nit) {
      se = (lane < nit - 1) ? colb[rs + lane] : nl;
      logit = lrelu(tpa[se * 4 + w] + pbsrc + aldn);
    }
    if (w == 0) sgn[lane] = se;
    float m = wave_max(logit);
    float raw = (lane < nit) ? __expf(logit - m) : 0.f;
    float den = wave_sum(raw);
    if (lane == 0) invs[w] = 1.f / den;
    __half2 a2 = __float2half2_rn(raw);
    alpha_u[w][lane] = *(unsigned int*)&a2;
    __syncthreads();
    int e = w;
    for (; e + 12 < nit; e += 16) {
      uint4 hv[4];
      unsigned int au[4];
#pragma unroll
      for (int i = 0; i < 4; i++) {
        int ei = e + i * 4;
        au[i] = alpha_u[hd][ei];
        hv[i] = *(const uint4*)(hbase + (size_t)sgn[ei] * 512);
      }
#pragma unroll
      for (int i = 0; i < 4; i++) {
        __half2 a2e = *(__half2*)&au[i];
        acc2[0] = __hfma2(a2e, *(__half2*)&hv[i].x, acc2[0]);
        acc2[1] = __hfma2(a2e, *(__half2*)&hv[i].y, acc2[1]);
        acc2[2] = __hfma2(a2e, *(__half2*)&hv[i].z, acc2[2]);
        acc2[3] = __hfma2(a2e, *(__half2*)&hv[i].w, acc2[3]);
      }
    }
    for (; e < nit; e += 4) {
      unsigned int au = alpha_u[hd][e];
      uint4 hv = *(const uint4*)(hbase + (size_t)sgn[e] * 512);
      __half2 a2e = *(__half2*)&au;
      acc2[0] = __hfma2(a2e, *(__half2*)&hv.x, acc2[0]);
      acc2[1] = __hfma2(a2e, *(__half2*)&hv.y, acc2[1]);
      acc2[2] = __hfma2(a2e, *(__half2*)&hv.z, acc2[2]);
      acc2[3] = __hfma2(a2e, *(__half2*)&hv.w, acc2[3]);
    }
  } else {
    float m = -3e38f;
    for (int i = lane; i < nit; i += 64) {
      int se = (i < nit - 1) ? colb[rs + i] : nl;
      m = fmaxf(m, lrelu(tpa[se * 4 + w] + pbsrc + aldn));
    }
    m = wave_max(m);
    float den = 0.f;
    for (int base = 0; base < nit; base += 64) {
      int cnt = min(64, nit - base);
      int se = nl;
      float raw = 0.f;
      if (lane < cnt) {
        int i = base + lane;
        se = (i < nit - 1) ? colb[rs + i] : nl;
        raw = __expf(lrelu(tpa[se * 4 + w] + pbsrc + aldn) - m);
      }
      if (w == 0) sgn[lane] = se;
      den += raw;
      __half2 a2 = __float2half2_rn(raw);
      alpha_u[w][lane] = *(unsigned int*)&a2;
      __syncthreads();
      for (int e = w; e < cnt; e += 4) {
        unsigned int au = alpha_u[hd][e];
        uint4 hv = *(const uint4*)(hbase + (size_t)sgn[e] * 512);
        __half2 a2e = *(__half2*)&au;
        acc2[0] = __hfma2(a2e, *(__half2*)&hv.x, acc2[0]);
        acc2[1] = __hfma2(a2e, *(__half2*)&hv.y, acc2[1]);
        acc2[2] = __hfma2(a2e, *(__half2*)&hv.z, acc2[2]);
        acc2[3] = __hfma2(a2e, *(__half2*)&hv.w, acc2[3]);
      }
      __syncthreads();
    }
    den = wave_sum(den);
    if (lane == 0) invs[w] = 1.f / den;
  }

  float fv[8];
#pragma unroll
  for (int j = 0; j < 4; j++) {
    float2 f2 = __half22float2(acc2[j]);
    fv[2 * j] = f2.x; fv[2 * j + 1] = f2.y;
  }
  *(float4*)&part[w][lane * 8] = make_float4(fv[0], fv[1], fv[2], fv[3]);
  *(float4*)&part[w][lane * 8 + 4] = make_float4(fv[4], fv[5], fv[6], fv[7]);
  __syncthreads();

  int c = 2 * (int)threadIdx.x;
  float inv = invs[c >> 7];
  float s0 = part[0][c] + part[1][c] + part[2][c] + part[3][c];
  float s1 = part[0][c + 1] + part[1][c + 1] + part[2][c + 1] + part[3][c + 1];
  float2 pv = *(const float2*)&pb[b * 512 + c];
  float v0 = lrelu(s0 * inv + pv.x + bias[c]);
  float v1 = lrelu(s1 * inv + pv.y + bias[c + 1]);
  float p1 = wave_sum(v0 + v1);
  float p2 = wave_sum(v0 * v0 + v1 * v1);
  if (lane == 0) { red[w] = p1; red[4 + w] = p2; }
  __syncthreads();
  if (threadIdx.x == 0) {
    float s1r = red[0] + red[1] + red[2] + red[3];
    float s2r = red[4] + red[5] + red[6] + red[7];
    float mu = s1r * (1.f / 512.f);
    float var = s2r * (1.f / 512.f) - mu * mu;
    bcs[0] = mu;
    bcs[1] = rsqrtf(var + EPSL);
  }
  __syncthreads();
  float mu = bcs[0], rstd = bcs[1];
  float o0 = (v0 - mu) * rstd * g[c] + beta[c];
  float o1 = (v1 - mu) * rstd * g[c + 1] + beta[c + 1];
  ushort2 st; st.x = f2h(o0); st.y = f2h(o1);
  *(ushort2*)&out[(size_t)n * 512 + c] = st;
}

// GAT2 aggregation + bias + leaky + resid + LayerNorm
__global__ __launch_bounds__(256) void agg_k(const unsigned short* __restrict__ h,
                                             const float* __restrict__ als, const float* __restrict__ ald,
                                             const float* __restrict__ bias,
                                             const float* __restrict__ g, const float* __restrict__ beta,
                                             const unsigned short* __restrict__ resid,
                                             unsigned short* __restrict__ out,
                                             const int* __restrict__ offs, const int* __restrict__ colb) {
  int blk = blockIdx.x;
  int b = blk & 7, nl = blk >> 3;
  int n = b * Nn + nl;
  int w = threadIdx.x >> 6, lane = threadIdx.x & 63;
  int rs = offs[nl];
  int nit = offs[nl + 1] - rs + 1;
  float aldn = ald[n * 4 + w];

  __shared__ unsigned int alpha_u[4][68];
  __shared__ int sgn[64];
  __shared__ float part[4][512];
  __shared__ float invs[4];
  __shared__ float red[8];
  __shared__ float bcs[2];

  __half2 acc2[4];
#pragma unroll
  for (int j = 0; j < 4; j++) acc2[j] = __float2half2_rn(0.f);

  const unsigned short* hbase = h + lane * 8;
  int hd = lane >> 4;

  if (nit <= 64) {
    int sg = n;
    float logit = -3e38f;
    if (lane < nit) {
      sg = (lane < nit - 1) ? colb[rs + lane] + b * Nn : n;
      logit = lrelu(als[sg * 4 + w] + aldn);
    }
    if (w == 0) sgn[lane] = sg;
    float m = wave_max(logit);
    float raw = (lane < nit) ? __expf(logit - m) : 0.f;
    float den = wave_sum(raw);
    if (lane == 0) invs[w] = 1.f / den;
    __half2 a2 = __float2half2_rn(raw);
    alpha_u[w][lane] = *(unsigned int*)&a2;
    __syncthreads();
    int e = w;
    for (; e + 12 < nit; e += 16) {
      uint4 hv[4];
      unsigned int au[4];
#pragma unroll
      for (int i = 0; i < 4; i++) {
        int ei = e + i * 4;
        au[i] = alpha_u[hd][ei];
        hv[i] = *(const uint4*)(hbase + (size_t)sgn[ei] * 512);
      }
#pragma unroll
      for (int i = 0; i < 4; i++) {
        __half2 a2e = *(__half2*)&au[i];
        acc2[0] = __hfma2(a2e, *(__half2*)&hv[i].x, acc2[0]);
        acc2[1] = __hfma2(a2e, *(__half2*)&hv[i].y, acc2[1]);
        acc2[2] = __hfma2(a2e, *(__half2*)&hv[i].z, acc2[2]);
        acc2[3] = __hfma2(a2e, *(__half2*)&hv[i].w, acc2[3]);
      }
    }
    for (; e < nit; e += 4) {
      unsigned int au = alpha_u[hd][e];
      uint4 hv = *(const uint4*)(hbase + (size_t)sgn[e] * 512);
      __half2 a2e = *(__half2*)&au;
      acc2[0] = __hfma2(a2e, *(__half2*)&hv.x, acc2[0]);
      acc2[1] = __hfma2(a2e, *(__half2*)&hv.y, acc2[1]);
      acc2[2] = __hfma2(a2e, *(__half2*)&hv.z, acc2[2]);
      acc2[3] = __hfma2(a2e, *(__half2*)&hv.w, acc2[3]);
    }
  } else {
    float m = -3e38f;
    for (int i = lane; i < nit; i += 64) {
      int sg = (i < nit - 1) ? colb[rs + i] + b * Nn : n;
      m = fmaxf(m, lrelu(als[sg * 4 + w] + aldn));
    }
    m = wave_max(m);
    float den = 0.f;
    for (int base = 0; base < nit; base += 64) {
      int cnt = min(64, nit - base);
      int sg = n;
      float raw = 0.f;
      if (lane < cnt) {
        int i = base + lane;
        sg = (i < nit - 1) ? colb[rs + i] + b * Nn : n;
        raw = __expf(lrelu(als[sg * 4 + w] + aldn) - m);
      }
      if (w == 0) sgn[lane] = sg;
      den += raw;
      __half2 a2 = __float2half2_rn(raw);
      alpha_u[w][lane] = *(unsigned int*)&a2;
      __syncthreads();
      for (int e = w; e < cnt; e += 4) {
        unsigned int au = alpha_u[hd][e];
        uint4 hv = *(const uint4*)(hbase + (size_t)sgn[e] * 512);
        __half2 a2e = *(__half2*)&au;
        acc2[0] = __hfma2(a2e, *(__half2*)&hv.x, acc2[0]);
        acc2[1] = __hfma2(a2e, *(__half2*)&hv.y, acc2[1]);
        acc2[2] = __hfma2(a2e, *(__half2*)&hv.z, acc2[2]);
        acc2[3] = __hfma2(a2e, *(__half2*)&hv.w, acc2[3]);
      }
      __syncthreads();
    }
    den = wave_sum(den);
    if (lane == 0) invs[w] = 1.f / den;
  }

  float fv[8];
#pragma unroll
  for (int j = 0; j < 4; j++) {
    float2 f2 = __half22float2(acc2[j]);
    fv[2 * j] = f2.x; fv[2 * j + 1] = f2.y;
  }
  *(float4*)&part[w][lane * 8] = make_float4(fv[0], fv[1], fv[2], fv[3]);
  *(float4*)&part[w][lane * 8 + 4] = make_float4(fv[4], fv[5], fv[6], fv[7]);
  __syncthreads();

  int c = 2 * (int)threadIdx.x;
  float inv = invs[c >> 7];
  float s0 = part[0][c] + part[1][c] + part[2][c] + part[3][c];
  float s1 = part[0][c + 1] + part[1][c + 1] + part[2][c + 1] + part[3][c + 1];
  float v0 = lrelu(s0 * inv + bias[c]);
  float v1 = lrelu(s1 * inv + bias[c + 1]);
  unsigned int rv = *(const unsigned int*)&resid[(size_t)n * 512 + c];
  __half2 rh = *(__half2*)&rv;
  float2 rf = __half22float2(rh);
  v0 += rf.x; v1 += rf.y;
  float p1 = wave_sum(v0 + v1);
  float p2 = wave_sum(v0 * v0 + v1 * v1);
  if (lane == 0) { red[w] = p1; red[4 + w] = p2; }
  __syncthreads();
  if (threadIdx.x == 0) {
    float s1r = red[0] + red[1] + red[2] + red[3];
    float s2r = red[4] + red[5] + red[6] + red[7];
    float mu = s1r * (1.f / 512.f);
    float var = s2r * (1.f / 512.f) - mu * mu;
    bcs[0] = mu;
    bcs[1] = rsqrtf(var + EPSL);
  }
  __syncthreads();
  float mu = bcs[0], rstd = bcs[1];
  float o0 = (v0 - mu) * rstd * g[c] + beta[c];
  float o1 = (v1 - mu) * rstd * g[c + 1] + beta[c + 1];
  ushort2 st; st.x = f2h(o0); st.y = f2h(o1);
  *(ushort2*)&out[(size_t)n * 512 + c] = st;
}

// ---------------- MFMA GEMM, B-RESIDENT, barrier-free K-loop + atomic als2/ald2 partials ----------------
__global__ __launch_bounds__(256) void gemm2_k(const unsigned short* __restrict__ A,
                                               const unsigned short* __restrict__ Bt,
                                               unsigned short* __restrict__ C,
                                               const float* __restrict__ As, const float* __restrict__ Ad,
                                               float* __restrict__ als2, float* __restrict__ ald2) {
  __shared__ unsigned short sB[64][520];
  int t = threadIdx.x;
  int lane = t & 63, w = t >> 6;
  int m0 = blockIdx.x * 128;
  int n0 = blockIdx.y * 64;
  const unsigned short* Bl = Bt + (size_t)((blockIdx.x + blockIdx.y * 125) & 7) * 262144;

#pragma unroll
  for (int q = 0; q < 16; q++) {
    int slot = q * 256 + t;
    int row = slot >> 6, c16 = (slot & 63) * 8;
    *(uint4*)&sB[row][c16] = *(const uint4*)(Bl + (size_t)(n0 + row) * 512 + c16);
  }
  __syncthreads();

  float4v acc[2][4];
#pragma unroll
  for (int m = 0; m < 2; m++)
#pragma unroll
    for (int nn = 0; nn < 4; nn++) acc[m][nn] = (float4v){0.f, 0.f, 0.f, 0.f};

  int r0 = m0 + w * 32 + (lane & 15);
  int kb = (lane >> 4) * 8;
  const unsigned short* a0p = A + (size_t)r0 * 512 + kb;
  const unsigned short* a1p = A + (size_t)(r0 + 16) * 512 + kb;
  int bc = lane & 15;

#pragma unroll
  for (int kf = 0; kf < 16; kf++) {
    int k0 = kf * 32;
    f16x8 af0 = *(const f16x8*)(a0p + k0);
    f16x8 af1 = *(const f16x8*)(a1p + k0);
    f16x8 bg0 = *(const f16x8*)&sB[bc][k0 + kb];
    f16x8 bg1 = *(const f16x8*)&sB[16 + bc][k0 + kb];
    f16x8 bg2 = *(const f16x8*)&sB[32 + bc][k0 + kb];
    f16x8 bg3 = *(const f16x8*)&sB[48 + bc][k0 + kb];
    acc[0][0] = __builtin_amdgcn_mfma_f32_16x16x32_f16(af0, bg0, acc[0][0], 0, 0, 0);
    acc[0][1] = __builtin_amdgcn_mfma_f32_16x16x32_f16(af0, bg1, acc[0][1], 0, 0, 0);
    acc[0][2] = __builtin_amdgcn_mfma_f32_16x16x32_f16(af0, bg2, acc[0][2], 0, 0, 0);
    acc[0][3] = __builtin_amdgcn_mfma_f32_16x16x32_f16(af0, bg3, acc[0][3], 0, 0, 0);
    acc[1][0] = __builtin_amdgcn_mfma_f32_16x16x32_f16(af1, bg0, acc[1][0], 0, 0, 0);
    acc[1][1] = __builtin_amdgcn_mfma_f32_16x16x32_f16(af1, bg1, acc[1][1], 0, 0, 0);
    acc[1][2] = __builtin_amdgcn_mfma_f32_16x16x32_f16(af1, bg2, acc[1][2], 0, 0, 0);
    acc[1][3] = __builtin_amdgcn_mfma_f32_16x16x32_f16(af1, bg3, acc[1][3], 0, 0, 0);
  }

  // als2/ald2 partials
  {
    int head = n0 >> 7;
    int cb = n0 & 127;
    float asv[4], adv[4];
#pragma unroll
    for (int nn = 0; nn < 4; nn++) {
      asv[nn] = As[head * 128 + cb + nn * 16 + bc];
      adv[nn] = Ad[head * 128 + cb + nn * 16 + bc];
    }
#pragma unroll
    for (int m = 0; m < 2; m++) {
#pragma unroll
      for (int r = 0; r < 4; r++) {
        float pa = 0.f, pd = 0.f;
#pragma unroll
        for (int nn = 0; nn < 4; nn++) { pa += acc[m][nn][r] * asv[nn]; pd += acc[m][nn][r] * adv[nn]; }
        for (int o = 1; o < 16; o <<= 1) { pa += __shfl_xor(pa, o); pd += __shfl_xor(pd, o); }
        if ((lane & 15) == 0) {
          int row = m0 + w * 32 + (lane >> 4) * 4 + m * 16 + r;
          atomicAdd(&als2[row * 4 + head], pa);
          atomicAdd(&ald2[row * 4 + head], pd);
        }
      }
    }
  }

  // C store via LDS restage; stride 72 ushorts (144B)
  __syncthreads();
  unsigned short* sC = &sB[0][0];
  int rb = w * 32 + (lane >> 4) * 4;
#pragma unroll
  for (int m = 0; m < 2; m++)
#pragma unroll
    for (int nn = 0; nn < 4; nn++)
#pragma unroll
      for (int r = 0; r < 4; r++)
        sC[(rb + m * 16 + r) * 72 + bc + nn * 16] = f2h(acc[m][nn][r]);
  __syncthreads();
#pragma unroll
  for (int p = 0; p < 4; p++) {
    int row = p * 32 + (t >> 3);
    int co = (t & 7) * 8;
    uint4 v = *(const uint4*)&sC[row * 72 + co];
    *(uint4*)&C[(size_t)(m0 + row) * 512 + n0 + co] = v;
  }
}

// ---------------- GAT3 GEMM ----------------
__global__ __launch_bounds__(256) void gemm3_k(const unsigned short* __restrict__ H,
                                               const unsigned short* __restrict__ W3t,
                                               const float* __restrict__ as3, const float* __restrict__ ad3,
                                               float* __restrict__ h3, float* __restrict__ als3,
                                               float* __restrict__ ald3) {
  int w = threadIdx.x >> 6, l = threadIdx.x & 63;
  int blk = blockIdx.x;
  int b = blk & 7, i = blk >> 3;
  int base = i * 64 + w * 16;
  int r16 = l & 15, g4 = l >> 4;
  int lrow_ld = min(base + r16, Nn - 1);
  float4v acc = (float4v){0.f, 0.f, 0.f, 0.f};
  const unsigned short* ha = H + (size_t)(b * Nn + lrow_ld) * 512 + g4 * 8;
  const unsigned short* wb = W3t + (size_t)r16 * 512 + g4 * 8;
#pragma unroll
  for (int kk = 0; kk < 16; kk++) {
    f16x8 a = *(const f16x8*)(ha + kk * 32);
    f16x8 bfr = *(const f16x8*)(wb + kk * 32);
    acc = __builtin_amdgcn_mfma_f32_16x16x32_f16(a, bfr, acc, 0, 0, 0);
  }
  int col = r16;
  float asv = (col < 13) ? as3[col] : 0.f;
  float adv = (col < 13) ? ad3[col] : 0.f;
#pragma unroll
  for (int r = 0; r < 4; r++) {
    float v = acc[r];
    int lrow = base + g4 * 4 + r;
    if (lrow < Nn) {
      int row = b * Nn + lrow;
      if (col < 13) h3[row * 13 + col] = v;
      float sa = v * asv, sd = v * adv;
      for (int o = 1; o < 16; o <<= 1) { sa += __shfl_xor(sa, o); sd += __shfl_xor(sd, o); }
      if (col == 0) { als3[row] = sa; ald3[row] = sd; }
    }
  }
}

// GAT3 aggregation + output assembly
__global__ __launch_bounds__(64) void agg3_k(const float* __restrict__ h3, const float* __restrict__ als3,
                                             const float* __restrict__ ald3, const float* __restrict__ b3,
                                             const float* __restrict__ tx, const int* __restrict__ offs,
                                             const int* __restrict__ colb, float* __restrict__ dout) {
  int blk = blockIdx.x, lane = threadIdx.x;
  int b = blk & 7, nl = blk >> 3;
  int n = b * Nn + nl;
  int rs = offs[nl], deg = offs[nl + 1] - rs;
  float aldn = ald3[n];
  float sl = lrelu(als3[n] + aldn);
  float a = 0.f, inv;
  if (deg <= 64) {
    int sgl = 0; float logit = -1e30f;
    if (lane < deg) { sgl = colb[rs + lane] + b * Nn; logit = lrelu(als3[sgl] + aldn); }
    float m = wave_max(fmaxf(logit, sl));
    float raw = (lane < deg) ? __expf(logit - m) : 0.f;
    float es = __expf(sl - m);
    inv = 1.f / (wave_sum(raw) + es);
    if (lane < 13) a = es * h3[n * 13 + lane];
    for (int e = 0; e < deg; e++) {
      float w = __shfl(raw, e);
      int sg = __shfl(sgl, e);
      if (lane < 13) a += w * h3[sg * 13 + lane];
    }
  } else {
    float m = sl;
    for (int e = lane; e < deg; e += 64) {
      int sg = colb[rs + e] + b * Nn;
      m = fmaxf(m, lrelu(als3[sg] + aldn));
    }
    m = wave_max(m);
    float es = __expf(sl - m);
    float den = (lane == 0) ? es : 0.f;
    if (lane < 13) a = es * h3[n * 13 + lane];
    for (int base = 0; base < deg; base += 64) {
      int cnt = min(64, deg - base);
      int sgl = 0; float raw = 0.f;
      if (lane < cnt) {
        sgl = colb[rs + base + lane] + b * Nn;
        raw = __expf(lrelu(als3[sgl] + aldn) - m);
      }
      den += raw;
      for (int e = 0; e < cnt; e++) {
        float w = __shfl(raw, e);
        int sg = __shfl(sgl, e);
        if (lane < 13) a += w * h3[sg * 13 + lane];
      }
    }
    inv = 1.f / wave_sum(den);
  }
  a *= inv;
  float hv = a + ((lane < 13) ? b3[lane] : 0.f);
  float txv = (lane < 10) ? tx[nl * 10 + lane] : 0.f;
  float pv = txv + hv;
  if (lane < 3) dout[PG_OFF + n * 3 + lane] = pv;
  float up = __shfl(hv, lane + 3);
  float xg = (lane < 3) ? pv : (txv + up);
  if (lane < 10) dout[XG_OFF + n * 10 + lane] = xg;
}

__global__ void ef_k(const int* __restrict__ tei, float* __restrict__ dout) {
  int blk = blockIdx.x;
  int b = blk & 7, i = blk >> 3;
  int j = i * 256 + threadIdx.x;
  int e = b * Ee + j;
  int sg = tei[j] + b * Nn;
  int dg = tei[Ee + j] + b * Nn;
  const float* pg = dout + PG_OFF;
  dout[EF_OFF + e * 3 + 0] = pg[dg * 3 + 0] - pg[sg * 3 + 0];
  dout[EF_OFF + e * 3 + 1] = pg[dg * 3 + 1] - pg[sg * 3 + 1];
  dout[EF_OFF + e * 3 + 2] = pg[dg * 3 + 2] - pg[sg * 3 + 2];
}

extern "C" void kernel_launch(void* const* d_in, const int* in_sizes, int n_in,
                              void* d_out, int out_size, void* d_ws, size_t ws_size,
                              hipStream_t stream) {
  const float* z = (const float*)d_in[0];
  const float* tx = (const float*)d_in[1];
  const int* tei = (const int*)d_in[2];
  const float* w1 = (const float*)d_in[3];
  const float* b1 = (const float*)d_in[4];
  const float* w2 = (const float*)d_in[5];
  const float* b2 = (const float*)d_in[6];
  const float* w3 = (const float*)d_in[7];
  const float* b3 = (const float*)d_in[8];
  const float* g1w = (const float*)d_in[9];
  const float* g1as = (const float*)d_in[10];
  const float* g1ad = (const float*)d_in[11];
  const float* g1b = (const float*)d_in[12];
  const float* ln1g = (const float*)d_in[13];
  const float* ln1b = (const float*)d_in[14];
  const float* g2w = (const float*)d_in[15];
  const float* g2as = (const float*)d_in[16];
  const float* g2ad = (const float*)d_in[17];
  const float* g2b = (const float*)d_in[18];
  const float* ln2g = (const float*)d_in[19];
  const float* ln2b = (const float*)d_in[20];
  const float* g3w = (const float*)d_in[21];
  const float* g3as = (const float*)d_in[22];
  const float* g3ad = (const float*)d_in[23];
  const float* g3b = (const float*)d_in[24];
  float* out = (float*)d_out;

  float* F = (float*)d_ws;
  float* pb_ = F + 0;
  float* l1_ = F + 8192;
  float* l2_ = F + 16384;
  float* s_ = F + 24576;
  float* pba_ = F + 30000;
  float* pbd_ = F + 30100;
  float* tpa_ = F + 100000;
  float* tpd_ = F + 164000;
  float* als2 = F + 228000;   // 64000, contiguous with ald2
  float* ald2 = F + 292000;   // 64000
  float* als3 = F + 356000;
  float* ald3 = F + 372000;
  float* h3_ = F + 388000;
  unsigned short* U = (unsigned short*)(F + 600000);
  unsigned short* hA = U;
  unsigned short* hB = U + 8192000;
  unsigned short* Bt = U + 16384000;
  unsigned short* W3t = U + 18481152;
  unsigned short* tp16 = U + 18489344;
  int* I = (int*)(F + 12000000);
  int* counts = I;
  int* cursor = I + 2000;
  int* offs = I + 4000;
  int* colb = I + 6001;

  // zero CSR scratch + als2/ald2 accumulators (contiguous -> one memset)
  hipMemsetAsync(counts, 0, 4000 * sizeof(int), stream);
  hipMemsetAsync(als2, 0, 128000 * sizeof(float), stream);

  // CSR of template graph
  hist_k<<<125, 256, 0, stream>>>(tei, counts);
  scan_k<<<1, 256, 0, stream>>>(counts, offs);
  place_k<<<125, 256, 0, stream>>>(tei, offs, cursor, colb);

  // weight preps + template table
  w2bf_k<<<dim3(16, 16), 256, 0, stream>>>(g2w, Bt);
  w3t_k<<<1, 256, 0, stream>>>(g3w, W3t);
  tp16_k<<<Nn, 256, 0, stream>>>(tx, g1w, g1as, g1ad, tp16, tpa_, tpd_);

  // style MLP + per-batch GAT1 partials
  lin_k<128, 1><<<512, 256, 0, stream>>>(z, w1, b1, l1_, 256);
  lin_k<256, 1><<<1024, 256, 0, stream>>>(l1_, w2, b2, l2_, 512);
  lin_k<512, 0><<<128, 256, 0, stream>>>(l2_, w3, b3, s_, 64);
  lin_k<64, 0><<<1024, 256, 0, stream>>>(s_, g1w + 10 * 512, nullptr, pb_, 512);
  pba_k<<<32, 64, 0, stream>>>(pb_, g1as, g1ad, pba_, pbd_);

  // GAT1 (template gather)
  agg1_k<<<NTOT, 256, 0, stream>>>(tp16, tpa_, tpd_, pba_, pbd_, pb_, g1b, ln1g, ln1b,
                                   hB, offs, colb);

  // GAT2: barrier-free B-resident GEMM w/ atomic als2/ald2, then aggregation
  gemm2_k<<<dim3(125, 8), 256, 0, stream>>>(hB, Bt, hA, g2as, g2ad, als2, ald2);
  agg_k<<<NTOT, 256, 0, stream>>>(hA, als2, ald2, g2b, ln2g, ln2b, hB, hB, offs, colb);

  // GAT3 + outputs
  gemm3_k<<<256, 256, 0, stream>>>(hB, W3t, g3as, g3ad, h3_, als3, ald3);
  agg3_k<<<NTOT, 64, 0, stream>>>(h3_, als3, ald3, g3b, tx, offs, colb, out);
  ef_k<<<1000, 256, 0, stream>>>(tei, out);
}